// Round 3
// baseline (56.759 us; speedup 1.0000x reference)
//
#include <hip/hip_runtime.h>

// BbRelProjection: per-sample closed-form QP projections.
//   QP1: y0 = clip(p0, lx, ux)
//   QP2: 2-point isotonic (pool to mean if out of order) then clip to [lx,ux]
//   QP3: 3-var chain: t from 3 stationary cases, clip t to [ly,uy],
//        ya/yb = clip(pa/pb, ly, t)
// Memory-bound: 16 f32/sample traffic. 2 samples/thread -> all accesses are
// float4 coalesced. Output is write-only: nontemporal stores keep the 168 MB
// of inputs resident in the 256 MiB L3 across graph replays (working set
// in+out = 268 MB marginally exceeds L3; writes were evicting input lines).
// NOTE: __builtin_nontemporal_* needs a NATIVE vector type, not HIP float4.

typedef float f32x4 __attribute__((ext_vector_type(4)));

__device__ __forceinline__ void project6(const float* __restrict__ p,
                                         const float* __restrict__ c,
                                         float* __restrict__ o) {
    const float lx = c[0], ux = c[1], ly = c[2], uy = c[3];
    // QP1: simple clamp
    o[0] = fminf(fmaxf(p[0], lx), ux);
    // QP2: 2-point isotonic regression then clip
    const float p1 = p[1], p2 = p[2];
    const float avg = 0.5f * (p1 + p2);
    const bool swap = p1 > p2;
    const float q1 = swap ? avg : p1;
    const float q2 = swap ? avg : p2;
    o[1] = fminf(fmaxf(q1, lx), ux);
    o[2] = fminf(fmaxf(q2, lx), ux);
    // QP3
    const float pa = p[3], pb = p[4], pc = p[5];
    const float m  = fmaxf(pa, pb);
    const float mn = fminf(pa, pb);
    const float t_all = (pa + pb + pc) / 3.0f;
    const float t_one = 0.5f * (pc + m);
    float t = (pc >= m) ? pc : ((t_all < mn) ? t_all : t_one);
    t = fminf(fmaxf(t, ly), uy);
    o[3] = fminf(fmaxf(pa, ly), t);   // clip order matches jnp.clip
    o[4] = fminf(fmaxf(pb, ly), t);
    o[5] = t;
}

__global__ void __launch_bounds__(256)
bbrel_proj_pair_kernel(const f32x4* __restrict__ yp,   // y_pred as f32x4 (3 per pair)
                       const f32x4* __restrict__ cp,   // constr as f32x4 (2 per pair)
                       f32x4* __restrict__ out,        // out as f32x4 (3 per pair)
                       int npairs) {
    const int t = blockIdx.x * blockDim.x + threadIdx.x;
    if (t >= npairs) return;

    const f32x4 v0 = yp[3 * t + 0];
    const f32x4 v1 = yp[3 * t + 1];
    const f32x4 v2 = yp[3 * t + 2];
    const f32x4 c0 = cp[2 * t + 0];
    const f32x4 c1 = cp[2 * t + 1];

    float p[12] = {v0.x, v0.y, v0.z, v0.w,
                   v1.x, v1.y, v1.z, v1.w,
                   v2.x, v2.y, v2.z, v2.w};
    float c[8]  = {c0.x, c0.y, c0.z, c0.w,
                   c1.x, c1.y, c1.z, c1.w};
    float o[12];

    project6(p,     c,     o);      // sample 2t
    project6(p + 6, c + 4, o + 6);  // sample 2t+1

    const f32x4 r0 = {o[0], o[1],  o[2],  o[3]};
    const f32x4 r1 = {o[4], o[5],  o[6],  o[7]};
    const f32x4 r2 = {o[8], o[9], o[10], o[11]};
    // Nontemporal: output is never re-read; don't let it pollute L2/L3
    // (keeps inputs L3-resident across graph replays).
    __builtin_nontemporal_store(r0, &out[3 * t + 0]);
    __builtin_nontemporal_store(r1, &out[3 * t + 1]);
    __builtin_nontemporal_store(r2, &out[3 * t + 2]);
}

// Scalar fallback for a possible odd-tail sample (not hit at BATCH=4194304).
__global__ void bbrel_proj_tail_kernel(const float* __restrict__ yp,
                                       const float* __restrict__ cp,
                                       float* __restrict__ out,
                                       int sample_idx) {
    if (threadIdx.x != 0 || blockIdx.x != 0) return;
    float p[6], c[4], o[6];
    for (int k = 0; k < 6; ++k) p[k] = yp[6 * sample_idx + k];
    for (int k = 0; k < 4; ++k) c[k] = cp[4 * sample_idx + k];
    project6(p, c, o);
    for (int k = 0; k < 6; ++k) out[6 * sample_idx + k] = o[k];
}

extern "C" void kernel_launch(void* const* d_in, const int* in_sizes, int n_in,
                              void* d_out, int out_size, void* d_ws, size_t ws_size,
                              hipStream_t stream) {
    const float* y_pred = (const float*)d_in[0];   // (N, 6) fp32
    const float* constr = (const float*)d_in[1];   // (N, 4) fp32
    float* out = (float*)d_out;                    // (N, 6) fp32

    const int n = in_sizes[0] / 6;
    const int npairs = n / 2;

    if (npairs > 0) {
        const int block = 256;
        const int grid = (npairs + block - 1) / block;
        bbrel_proj_pair_kernel<<<grid, block, 0, stream>>>(
            (const f32x4*)y_pred, (const f32x4*)constr, (f32x4*)out, npairs);
    }
    if (n & 1) {
        bbrel_proj_tail_kernel<<<1, 64, 0, stream>>>(y_pred, constr, out, n - 1);
    }
}

// Round 4
// 46.020 us; speedup vs baseline: 1.2333x; 1.2333x over previous
//
#include <hip/hip_runtime.h>

// BbRelProjection: per-sample closed-form QP projections.
//   QP1: y0 = clip(p0, lx, ux)
//   QP2: 2-point isotonic (pool to mean if out of order) then clip to [lx,ux]
//   QP3: 3-var chain: t from 3 stationary cases, clip t to [ly,uy],
//        ya/yb = clip(pa/pb, ly, t)
// Memory-bound: 16 f32/sample traffic. 2 samples/thread -> all accesses are
// float4 coalesced. 268.5 MB total traffic -> ~42.6 us floor at 6.3 TB/s;
// measured 46.1 us (~92%).
// NOTE (round-2/3 post-mortem): __builtin_nontemporal_store on the output
// REGRESSED (46->57 us, WRITE_SIZE 98->130+ MB): gfx950 nt stores bypass
// L2/L3 write coalescing and amplify HBM write traffic. Plain stores win.

__device__ __forceinline__ void project6(const float* __restrict__ p,
                                         const float* __restrict__ c,
                                         float* __restrict__ o) {
    const float lx = c[0], ux = c[1], ly = c[2], uy = c[3];
    // QP1: simple clamp
    o[0] = fminf(fmaxf(p[0], lx), ux);
    // QP2: 2-point isotonic regression then clip
    const float p1 = p[1], p2 = p[2];
    const float avg = 0.5f * (p1 + p2);
    const bool swap = p1 > p2;
    const float q1 = swap ? avg : p1;
    const float q2 = swap ? avg : p2;
    o[1] = fminf(fmaxf(q1, lx), ux);
    o[2] = fminf(fmaxf(q2, lx), ux);
    // QP3
    const float pa = p[3], pb = p[4], pc = p[5];
    const float m  = fmaxf(pa, pb);
    const float mn = fminf(pa, pb);
    const float t_all = (pa + pb + pc) / 3.0f;
    const float t_one = 0.5f * (pc + m);
    float t = (pc >= m) ? pc : ((t_all < mn) ? t_all : t_one);
    t = fminf(fmaxf(t, ly), uy);
    o[3] = fminf(fmaxf(pa, ly), t);   // clip order matches jnp.clip
    o[4] = fminf(fmaxf(pb, ly), t);
    o[5] = t;
}

__global__ void __launch_bounds__(256)
bbrel_proj_pair_kernel(const float4* __restrict__ yp,   // y_pred as float4 (3 per pair)
                       const float4* __restrict__ cp,   // constr as float4 (2 per pair)
                       float4* __restrict__ out,        // out as float4 (3 per pair)
                       int npairs) {
    const int t = blockIdx.x * blockDim.x + threadIdx.x;
    if (t >= npairs) return;

    const float4 v0 = yp[3 * t + 0];
    const float4 v1 = yp[3 * t + 1];
    const float4 v2 = yp[3 * t + 2];
    const float4 c0 = cp[2 * t + 0];
    const float4 c1 = cp[2 * t + 1];

    float p[12] = {v0.x, v0.y, v0.z, v0.w,
                   v1.x, v1.y, v1.z, v1.w,
                   v2.x, v2.y, v2.z, v2.w};
    float c[8]  = {c0.x, c0.y, c0.z, c0.w,
                   c1.x, c1.y, c1.z, c1.w};
    float o[12];

    project6(p,     c,     o);      // sample 2t
    project6(p + 6, c + 4, o + 6);  // sample 2t+1

    const float4 r0 = {o[0], o[1],  o[2],  o[3]};
    const float4 r1 = {o[4], o[5],  o[6],  o[7]};
    const float4 r2 = {o[8], o[9], o[10], o[11]};
    out[3 * t + 0] = r0;
    out[3 * t + 1] = r1;
    out[3 * t + 2] = r2;
}

// Scalar fallback for a possible odd-tail sample (not hit at BATCH=4194304).
__global__ void bbrel_proj_tail_kernel(const float* __restrict__ yp,
                                       const float* __restrict__ cp,
                                       float* __restrict__ out,
                                       int sample_idx) {
    if (threadIdx.x != 0 || blockIdx.x != 0) return;
    float p[6], c[4], o[6];
    for (int k = 0; k < 6; ++k) p[k] = yp[6 * sample_idx + k];
    for (int k = 0; k < 4; ++k) c[k] = cp[4 * sample_idx + k];
    project6(p, c, o);
    for (int k = 0; k < 6; ++k) out[6 * sample_idx + k] = o[k];
}

extern "C" void kernel_launch(void* const* d_in, const int* in_sizes, int n_in,
                              void* d_out, int out_size, void* d_ws, size_t ws_size,
                              hipStream_t stream) {
    const float* y_pred = (const float*)d_in[0];   // (N, 6) fp32
    const float* constr = (const float*)d_in[1];   // (N, 4) fp32
    float* out = (float*)d_out;                    // (N, 6) fp32

    const int n = in_sizes[0] / 6;
    const int npairs = n / 2;

    if (npairs > 0) {
        const int block = 256;
        const int grid = (npairs + block - 1) / block;
        bbrel_proj_pair_kernel<<<grid, block, 0, stream>>>(
            (const float4*)y_pred, (const float4*)constr, (float4*)out, npairs);
    }
    if (n & 1) {
        bbrel_proj_tail_kernel<<<1, 64, 0, stream>>>(y_pred, constr, out, n - 1);
    }
}

// Round 5
// 43.197 us; speedup vs baseline: 1.3139x; 1.0654x over previous
//
#include <hip/hip_runtime.h>

// BbRelProjection: per-sample closed-form QP projections (see project6).
// Memory-bound. Round-4 finding: steady-state HBM traffic is only 184.6 MB
// (L3 serves half the reads) -> HBM floor ~29 us, but direct strided float4
// access (lane stride 48 B, ~24 lines/instr) left us at 46 us = 4.0 TB/s —
// TA/L1 line-serialization bound, not HBM bound.
// Fix: LDS-staged transpose. Coalesced unit-stride global <-> LDS staging
// (8 lines/instr), per-pair compute out of LDS. LDS reads at word-stride 12
// are bank-optimal (12*8 = 96 = 0 mod 32, distinct words -> 8 words/bank =
// minimum cycles). Results written in place (same LDS slots), then coalesced
// store rounds. 20 KB LDS/block -> 8 blocks/CU -> full 32-wave occupancy.
// Round-2/3 post-mortem: nontemporal stores REGRESSED (write amplification
// 98 -> 130+ MB); plain stores only.

#define THREADS 256
#define PAIRS_PER_BLOCK 256   // 512 samples per block

__device__ __forceinline__ void project6(const float* __restrict__ p,
                                         const float* __restrict__ c,
                                         float* __restrict__ o) {
    const float lx = c[0], ux = c[1], ly = c[2], uy = c[3];
    // QP1: simple clamp
    o[0] = fminf(fmaxf(p[0], lx), ux);
    // QP2: 2-point isotonic regression then clip
    const float p1 = p[1], p2 = p[2];
    const float avg = 0.5f * (p1 + p2);
    const bool swap = p1 > p2;
    const float q1 = swap ? avg : p1;
    const float q2 = swap ? avg : p2;
    o[1] = fminf(fmaxf(q1, lx), ux);
    o[2] = fminf(fmaxf(q2, lx), ux);
    // QP3
    const float pa = p[3], pb = p[4], pc = p[5];
    const float m  = fmaxf(pa, pb);
    const float mn = fminf(pa, pb);
    const float t_all = (pa + pb + pc) / 3.0f;
    const float t_one = 0.5f * (pc + m);
    float t = (pc >= m) ? pc : ((t_all < mn) ? t_all : t_one);
    t = fminf(fmaxf(t, ly), uy);
    o[3] = fminf(fmaxf(pa, ly), t);   // clip order matches jnp.clip
    o[4] = fminf(fmaxf(pb, ly), t);
    o[5] = t;
}

__global__ void __launch_bounds__(THREADS)
bbrel_proj_lds_kernel(const float4* __restrict__ yp,   // y_pred as float4 (3 per pair)
                      const float4* __restrict__ cp,   // constr as float4 (2 per pair)
                      float4* __restrict__ out,        // out as float4 (3 per pair)
                      int npairs) {
    __shared__ float4 ly[PAIRS_PER_BLOCK * 3];  // 12 KB, reused for output
    __shared__ float4 lc[PAIRS_PER_BLOCK * 2];  // 8 KB

    const int tid = threadIdx.x;
    const int pairBase = blockIdx.x * PAIRS_PER_BLOCK;
    const int nHere = min(PAIRS_PER_BLOCK, npairs - pairBase);
    const int f4Base = pairBase * 3;
    const int c4Base = pairBase * 2;

    // ---- stage in (coalesced unit-stride rounds) ----
    if (nHere == PAIRS_PER_BLOCK) {
        ly[tid]       = yp[f4Base + tid];
        ly[tid + 256] = yp[f4Base + tid + 256];
        ly[tid + 512] = yp[f4Base + tid + 512];
        lc[tid]       = cp[c4Base + tid];
        lc[tid + 256] = cp[c4Base + tid + 256];
    } else {
        for (int f = tid; f < nHere * 3; f += THREADS) ly[f] = yp[f4Base + f];
        for (int f = tid; f < nHere * 2; f += THREADS) lc[f] = cp[c4Base + f];
    }
    __syncthreads();

    // ---- compute: thread tid owns pair tid (2 samples), in-place in LDS ----
    if (tid < nHere) {
        const float4 v0 = ly[3 * tid + 0];
        const float4 v1 = ly[3 * tid + 1];
        const float4 v2 = ly[3 * tid + 2];
        const float4 c0 = lc[2 * tid + 0];
        const float4 c1 = lc[2 * tid + 1];

        float p[12] = {v0.x, v0.y, v0.z, v0.w,
                       v1.x, v1.y, v1.z, v1.w,
                       v2.x, v2.y, v2.z, v2.w};
        float c[8]  = {c0.x, c0.y, c0.z, c0.w,
                       c1.x, c1.y, c1.z, c1.w};
        float o[12];

        project6(p,     c,     o);      // sample 2*pair
        project6(p + 6, c + 4, o + 6);  // sample 2*pair+1

        const float4 r0 = {o[0], o[1],  o[2],  o[3]};
        const float4 r1 = {o[4], o[5],  o[6],  o[7]};
        const float4 r2 = {o[8], o[9], o[10], o[11]};
        ly[3 * tid + 0] = r0;   // own slots only -> no hazard
        ly[3 * tid + 1] = r1;
        ly[3 * tid + 2] = r2;
    }
    __syncthreads();

    // ---- stage out (coalesced unit-stride rounds) ----
    if (nHere == PAIRS_PER_BLOCK) {
        out[f4Base + tid]       = ly[tid];
        out[f4Base + tid + 256] = ly[tid + 256];
        out[f4Base + tid + 512] = ly[tid + 512];
    } else {
        for (int f = tid; f < nHere * 3; f += THREADS) out[f4Base + f] = ly[f];
    }
}

// Scalar fallback for a possible odd-tail sample (not hit at BATCH=4194304).
__global__ void bbrel_proj_tail_kernel(const float* __restrict__ yp,
                                       const float* __restrict__ cp,
                                       float* __restrict__ out,
                                       int sample_idx) {
    if (threadIdx.x != 0 || blockIdx.x != 0) return;
    float p[6], c[4], o[6];
    for (int k = 0; k < 6; ++k) p[k] = yp[6 * sample_idx + k];
    for (int k = 0; k < 4; ++k) c[k] = cp[4 * sample_idx + k];
    project6(p, c, o);
    for (int k = 0; k < 6; ++k) out[6 * sample_idx + k] = o[k];
}

extern "C" void kernel_launch(void* const* d_in, const int* in_sizes, int n_in,
                              void* d_out, int out_size, void* d_ws, size_t ws_size,
                              hipStream_t stream) {
    const float* y_pred = (const float*)d_in[0];   // (N, 6) fp32
    const float* constr = (const float*)d_in[1];   // (N, 4) fp32
    float* out = (float*)d_out;                    // (N, 6) fp32

    const int n = in_sizes[0] / 6;
    const int npairs = n / 2;

    if (npairs > 0) {
        const int grid = (npairs + PAIRS_PER_BLOCK - 1) / PAIRS_PER_BLOCK;
        bbrel_proj_lds_kernel<<<grid, THREADS, 0, stream>>>(
            (const float4*)y_pred, (const float4*)constr, (float4*)out, npairs);
    }
    if (n & 1) {
        bbrel_proj_tail_kernel<<<1, 64, 0, stream>>>(y_pred, constr, out, n - 1);
    }
}